// Round 1
// baseline (437.647 us; speedup 1.0000x reference)
//
#include <hip/hip_runtime.h>
#include <type_traits>
#include <cmath>
#include <cstdint>

#define NRAYS     262144
#define HASHMAP   524288
#define DIM       256
#define NMID      6
#define MBLK      64
#define ALPHA     512.0f          // power-of-2 activation scale: lifts h (~1e-4) out of
#define INV_ALPHA (1.0f / 512.0f) // fp16 subnormal range; exact, removed at output.

typedef _Float16 half8 __attribute__((ext_vector_type(8)));
typedef _Float16 half2 __attribute__((ext_vector_type(2)));
typedef float  floatx4 __attribute__((ext_vector_type(4)));

// ws layout (_Float16 elements) — fp16 weights, single product per MFMA:
//   [0, 8192):        W_in  fragments [nc:16][lane:64][j:8]  (K padded 16->32 with zeros)
//   [8192, 401408):   W_mid fragments [L:6][kc:8][nc:16][lane:64][j:8]
// fp16 numerics validated (R7 pass): absmax 1.19e-7, 3.3x under threshold.
//
// SESSION INVARIANT (R8 post-mortem): keep arch VGPR allocation <= 128 and use
// floatx4 accumulators only. Every kernel that allocated >128 VGPRs (R2,R3,R8)
// failed with a ~4-5e-6 few-elements-wrong signature (accum_offset/AGPR-boundary
// miscompile class); every <=128 kernel passed. Hence: launch_bounds (256,4)
// (cap=128) + NO explicit deep prefetch (keeps demand ~105 regs, no spill).
#define WIN_ELEMS   8192
#define WL_ELEMS    65536
#define WKC_ELEMS   8192
#define WNC_ELEMS   512

// Gray-coded XOR swizzle (R4, frozen — conflict counter insensitive to choice).
__device__ __forceinline__ int sw_idx(int r, int k) {
  int s = (r ^ (r >> 1)) & 7;
  return (r << 8) + ((((k >> 3) ^ s) << 3) | (k & 7));
}

__global__ __launch_bounds__(256) void prep_weights(
    const float* __restrict__ W_in, const float* __restrict__ W_mid,
    _Float16* __restrict__ wsh)
{
  int tid = blockIdx.x * 256 + threadIdx.x;
  int pos = tid & 511;             // lane*8 + j
  int lane = pos >> 3, j = pos & 7;
  int kk = ((lane >> 4) << 3) + j; // quad*8 + j, 0..31
  if (tid < WIN_ELEMS) {
    int nc = tid >> 9;
    int n = (nc << 4) + (lane & 15);
    float v = (kk < 16) ? W_in[kk * DIM + n] : 0.f;
    wsh[nc * WNC_ELEMS + pos] = (_Float16)v;
  } else if (tid < WIN_ELEMS + 6 * WL_ELEMS) {
    int u = tid - WIN_ELEMS;
    int fid = u >> 9;              // 0..767
    int L   = fid >> 7;
    int rem = fid & 127;
    int kc  = rem >> 4;
    int nc  = rem & 15;
    int k = (kc << 5) + kk;
    int n = (nc << 4) + (lane & 15);
    float v = W_mid[L * (DIM * DIM) + k * DIM + n];
    wsh[WIN_ELEMS + L * WL_ELEMS + kc * WKC_ELEMS + nc * WNC_ELEMS + pos] = (_Float16)v;
  }
}

// (256,4): VGPR cap 128 (the correctness invariant) AND 4 blocks/CU (32 KB LDS)
// for cross-block phase overlap. Latency hiding via TLP (16 waves/CU), not
// register prefetch: per kc, 4 waves x 16 MFMA (~300 cyc/SIMD) covers ~200-cyc
// L2 latency of the un-prefetched weight loads.
__global__ __launch_bounds__(256, 4) void mlp_fused(
    const float* __restrict__ x,
    const float* __restrict__ table1,
    const float* __restrict__ table2,
    const _Float16* __restrict__ wsh,
    const float* __restrict__ b_in,
    const float* __restrict__ b_mid,
    const float* __restrict__ W_out,
    const float* __restrict__ b_out,
    float* __restrict__ out,
    int res0, int res1, int res2, int res3)
{
  __shared__ __align__(16) _Float16 hs[MBLK * 256];  // alpha*relu(h) in fp16, swizzled [ray][k]

  const int tid  = threadIdx.x;
  const int lane = tid & 63;
  const int wave = tid >> 6;
  const int col  = lane & 15;
  const int quad = lane >> 4;
  const int rbase = blockIdx.x * MBLK;

  // ---------------- hash-grid encode: 512 (ray,enc,level) tasks, 2 per thread ----------------
  #pragma unroll
  for (int i = 0; i < 2; ++i) {
    int task = tid + (i << 8);
    int r   = task & 63;
    int el  = task >> 6;           // 0..7
    int enc = el >> 2, lev = el & 3;
    const float* xp = x + (size_t)(rbase + r) * 4 + enc * 2;
    float px = xp[0], py = xp[1];
    int res = (lev == 0) ? res0 : (lev == 1) ? res1 : (lev == 2) ? res2 : res3;
    float fres = (float)res;
    float xf = px * fres, yf = py * fres;
    float xi = floorf(xf), yi = floorf(yf);
    float fx = xf - xi,  fy = yf - yi;
    uint32_t ix = (uint32_t)xi, iy = (uint32_t)yi;
    const float2* tab = (const float2*)(enc ? table2 : table1) + (size_t)lev * HASHMAP;
    float f0 = 0.f, f1 = 0.f;
    #pragma unroll
    for (int c = 0; c < 4; ++c) {                    // corners (0,0),(0,1),(1,0),(1,1)
      uint32_t c0 = (uint32_t)(c >> 1), c1 = (uint32_t)(c & 1);
      uint32_t h = ((ix + c0) ^ ((iy + c1) * 2654435761u)) & (uint32_t)(HASHMAP - 1);
      float2 v = tab[h];
      float w = (c0 ? fx : 1.f - fx) * (c1 ? fy : 1.f - fy);
      f0 += w * v.x;
      f1 += w * v.y;
    }
    int cb = enc * 8 + lev * 2;                      // emb column (concat: enc-major, level, feat)
    half2 hp = {(_Float16)(f0 * ALPHA), (_Float16)(f1 * ALPHA)};
    *(half2*)&hs[sw_idx(r, cb)] = hp;
  }
  // zero K-pad columns 16..31 for the first (K=32) MFMA
  for (int i = tid; i < MBLK * 16; i += 256) {
    int r = i >> 4, k = 16 + (i & 15);
    hs[sw_idx(r, k)] = (_Float16)0.f;
  }
  __syncthreads();

  floatx4 acc[4][4];

  // One dense layer: D(64x256) = A(64xK) * B(Kx256); A = alpha*h (fp16, LDS),
  // B = fp16 weights (pre-permuted fragments, L2-resident).
  auto run_layer = [&](auto kc_const, const _Float16* __restrict__ wbase,
                       const float* __restrict__ bias_ptr) {
    constexpr int KCOUNT = decltype(kc_const)::value;
    const floatx4 zv = {0.f, 0.f, 0.f, 0.f};
    #pragma unroll
    for (int mt = 0; mt < 4; ++mt)
      #pragma unroll
      for (int nl = 0; nl < 4; ++nl)
        acc[mt][nl] = zv;

    const _Float16* wlane = wbase + wave * 4 * WNC_ELEMS + lane * 8;

    #pragma clang loop unroll(disable)               // keep VGPR pressure flat (<=128)
    for (int kc = 0; kc < KCOUNT; ++kc) {
      half8 b[4];
      const _Float16* wk = wlane + kc * WKC_ELEMS;
      #pragma unroll
      for (int nl = 0; nl < 4; ++nl)
        b[nl] = *(const half8*)(wk + nl * WNC_ELEMS);
      half8 a[4];
      #pragma unroll
      for (int mt = 0; mt < 4; ++mt) {
        // A-fragment: m = lane&15 (within m-tile), k = kc*32 + quad*8 + j
        int idx = sw_idx(mt * 16 + col, kc * 32 + quad * 8);
        a[mt] = *(const half8*)&hs[idx];
      }
      #pragma unroll
      for (int nl = 0; nl < 4; ++nl)
        #pragma unroll
        for (int mt = 0; mt < 4; ++mt)
          acc[mt][nl] = __builtin_amdgcn_mfma_f32_16x16x32_f16(a[mt], b[nl], acc[mt][nl], 0, 0, 0);
    }
    __syncthreads();   // all waves done reading hs before overwrite
    #pragma unroll
    for (int nl = 0; nl < 4; ++nl) {
      int n = wave * 64 + nl * 16 + col;
      float biasA = bias_ptr[n] * ALPHA;             // bias scaled by alpha
      #pragma unroll
      for (int mt = 0; mt < 4; ++mt) {
        #pragma unroll
        for (int r = 0; r < 4; ++r) {
          // D layout: col = lane&15, row = quad*4 + r
          int m = mt * 16 + quad * 4 + r;
          float hv = fmaxf(acc[mt][nl][r] + biasA, 0.f);   // ReLU pre-next-matmul
          hs[sw_idx(m, n)] = (_Float16)hv;
        }
      }
    }
    __syncthreads();
  };

  run_layer(std::integral_constant<int, 1>{}, wsh, b_in);
  #pragma clang loop unroll(disable)
  for (int L = 0; L < NMID; ++L)
    run_layer(std::integral_constant<int, 8>{}, wsh + WIN_ELEMS + L * WL_ELEMS, b_mid + L * DIM);

  // ---------------- output layer: out = (alpha*relu h).W_out / alpha + b_out ----
  // R9: vectorized epilogue. sw_idx keeps k's low 3 bits contiguous, so an
  // 8-aligned half8 LDS read is legal: 8x ds_read_b128 + 16x float4 W_out loads
  // replace 64 ds_read_u16 + 64 scalar global loads per thread.
  {
    int m = tid >> 2, seg = tid & 3;          // same-m threads adjacent -> shuffle reduce
    float sum = 0.f;
    #pragma unroll
    for (int i = 0; i < 8; ++i) {
      int k = (seg << 6) + (i << 3);          // 8-aligned group within this thread's 64-wide segment
      half8 hv = *(const half8*)&hs[sw_idx(m, k)];
      float4 w0 = *(const float4*)&W_out[k];
      float4 w1 = *(const float4*)&W_out[k + 4];
      sum += (float)hv[0] * w0.x + (float)hv[1] * w0.y
           + (float)hv[2] * w0.z + (float)hv[3] * w0.w
           + (float)hv[4] * w1.x + (float)hv[5] * w1.y
           + (float)hv[6] * w1.z + (float)hv[7] * w1.w;
    }
    sum += __shfl_xor(sum, 1);
    sum += __shfl_xor(sum, 2);
    if (seg == 0) out[rbase + m] = sum * INV_ALPHA + b_out[0];
  }
}

extern "C" void kernel_launch(void* const* d_in, const int* in_sizes, int n_in,
                              void* d_out, int out_size, void* d_ws, size_t ws_size,
                              hipStream_t stream)
{
  const float* x      = (const float*)d_in[0];
  const float* table1 = (const float*)d_in[1];
  const float* table2 = (const float*)d_in[2];
  const float* W_in   = (const float*)d_in[3];
  const float* b_in   = (const float*)d_in[4];
  const float* W_mid  = (const float*)d_in[5];
  const float* b_mid  = (const float*)d_in[6];
  const float* W_out  = (const float*)d_in[7];
  const float* b_out  = (const float*)d_in[8];
  float* out  = (float*)d_out;
  _Float16* wsh = (_Float16*)d_ws;

  // Resolutions: identical double-precision op sequence as the Python module (same libm).
  double b = exp((log(512.0) - log(16.0)) / 3.0);
  int res[4];
  for (int l = 0; l < 4; ++l) res[l] = (int)floor(16.0 * pow(b, (double)l));

  int prep_total = WIN_ELEMS + 6 * WL_ELEMS;   // 401408 = 1568 * 256
  prep_weights<<<prep_total / 256, 256, 0, stream>>>(W_in, W_mid, wsh);
  mlp_fused<<<NRAYS / MBLK, 256, 0, stream>>>(x, table1, table2, wsh, b_in, b_mid,
                                              W_out, b_out, out,
                                              res[0], res[1], res[2], res[3]);
}

// Round 4
// 400.863 us; speedup vs baseline: 1.0918x; 1.0918x over previous
//
#include <hip/hip_runtime.h>
#include <type_traits>
#include <cmath>
#include <cstdint>

#define NRAYS     262144
#define HASHMAP   524288
#define DIM       256
#define NMID      6
#define MBLK      64
#define ALPHA     512.0f          // power-of-2 activation scale: lifts h (~1e-4) out of
#define INV_ALPHA (1.0f / 512.0f) // fp16 subnormal range; exact, removed at output.

typedef _Float16 half8 __attribute__((ext_vector_type(8)));
typedef _Float16 half2 __attribute__((ext_vector_type(2)));
typedef float  floatx4 __attribute__((ext_vector_type(4)));

// ws layout (_Float16 elements) — fp16 weights, single product per MFMA:
//   [0, 8192):        W_in  fragments [nc:16][lane:64][j:8]  (K padded 16->32 with zeros)
//   [8192, 401408):   W_mid fragments [L:6][kc:8][nc:16][lane:64][j:8]
// fp16 numerics validated (R7 pass): absmax 1.19e-7, 3.3x under threshold.
//
// SESSION INVARIANT (updated R11 post-mortem): the ~4-7e-6 few-elements-wrong
// miscompile class fires whenever arch-side register demand exceeds the 64-reg
// half of the (256,4) 128-cap split — operands then migrate through
// v_accvgpr_* at the AGPR boundary and a few elements corrupt. R9 passes at
// exactly arch=64 + acc=64. Rules:
//   (a) NEVER swap MFMA operand roles;
//   (b) NEVER add pre-MFMA register state beyond R9's b[4]+a[4] (no prefetch
//       double-buffers, no extra pre-barrier float4 state) — only REDUCE;
//   (c) floatx4 accumulators only; launch_bounds (256,4) stays.
// R12 edits vs R9: (1) strength-reduced A addressing (register-NEGATIVE:
// removes per-mt sw_idx temps); (2) s_setprio around MFMA cluster (0 regs).
#define WIN_ELEMS   8192
#define WL_ELEMS    65536
#define WKC_ELEMS   8192
#define WNC_ELEMS   512

// Gray-coded XOR swizzle (R4, frozen — conflict counter insensitive to choice).
__device__ __forceinline__ int sw_idx(int r, int k) {
  int s = (r ^ (r >> 1)) & 7;
  return (r << 8) + ((((k >> 3) ^ s) << 3) | (k & 7));
}

__global__ __launch_bounds__(256) void prep_weights(
    const float* __restrict__ W_in, const float* __restrict__ W_mid,
    _Float16* __restrict__ wsh)
{
  int tid = blockIdx.x * 256 + threadIdx.x;
  int pos = tid & 511;             // lane*8 + j
  int lane = pos >> 3, j = pos & 7;
  int kk = ((lane >> 4) << 3) + j; // quad*8 + j, 0..31
  if (tid < WIN_ELEMS) {
    int nc = tid >> 9;
    int n = (nc << 4) + (lane & 15);
    float v = (kk < 16) ? W_in[kk * DIM + n] : 0.f;
    wsh[nc * WNC_ELEMS + pos] = (_Float16)v;
  } else if (tid < WIN_ELEMS + 6 * WL_ELEMS) {
    int u = tid - WIN_ELEMS;
    int fid = u >> 9;              // 0..767
    int L   = fid >> 7;
    int rem = fid & 127;
    int kc  = rem >> 4;
    int nc  = rem & 15;
    int k = (kc << 5) + kk;
    int n = (nc << 4) + (lane & 15);
    float v = W_mid[L * (DIM * DIM) + k * DIM + n];
    wsh[WIN_ELEMS + L * WL_ELEMS + kc * WKC_ELEMS + nc * WNC_ELEMS + pos] = (_Float16)v;
  }
}

// (256,4): VGPR cap 128 (the correctness invariant) AND 4 blocks/CU (32 KB LDS)
// for cross-block phase overlap. Latency hiding via TLP (16 waves/CU), not
// register prefetch: per kc, 4 waves x 16 MFMA (~300 cyc/SIMD) covers ~200-cyc
// L2 latency of the un-prefetched weight loads.
__global__ __launch_bounds__(256, 4) void mlp_fused(
    const float* __restrict__ x,
    const float* __restrict__ table1,
    const float* __restrict__ table2,
    const _Float16* __restrict__ wsh,
    const float* __restrict__ b_in,
    const float* __restrict__ b_mid,
    const float* __restrict__ W_out,
    const float* __restrict__ b_out,
    float* __restrict__ out,
    int res0, int res1, int res2, int res3)
{
  __shared__ __align__(16) _Float16 hs[MBLK * 256];  // alpha*relu(h) in fp16, swizzled [ray][k]

  const int tid  = threadIdx.x;
  const int lane = tid & 63;
  const int wave = tid >> 6;
  const int col  = lane & 15;
  const int quad = lane >> 4;
  const int rbase = blockIdx.x * MBLK;

  // ---------------- hash-grid encode: 512 (ray,enc,level) tasks, 2 per thread ----------------
  #pragma unroll
  for (int i = 0; i < 2; ++i) {
    int task = tid + (i << 8);
    int r   = task & 63;
    int el  = task >> 6;           // 0..7
    int enc = el >> 2, lev = el & 3;
    const float* xp = x + (size_t)(rbase + r) * 4 + enc * 2;
    float px = xp[0], py = xp[1];
    int res = (lev == 0) ? res0 : (lev == 1) ? res1 : (lev == 2) ? res2 : res3;
    float fres = (float)res;
    float xf = px * fres, yf = py * fres;
    float xi = floorf(xf), yi = floorf(yf);
    float fx = xf - xi,  fy = yf - yi;
    uint32_t ix = (uint32_t)xi, iy = (uint32_t)yi;
    const float2* tab = (const float2*)(enc ? table2 : table1) + (size_t)lev * HASHMAP;
    float f0 = 0.f, f1 = 0.f;
    #pragma unroll
    for (int c = 0; c < 4; ++c) {                    // corners (0,0),(0,1),(1,0),(1,1)
      uint32_t c0 = (uint32_t)(c >> 1), c1 = (uint32_t)(c & 1);
      uint32_t h = ((ix + c0) ^ ((iy + c1) * 2654435761u)) & (uint32_t)(HASHMAP - 1);
      float2 v = tab[h];
      float w = (c0 ? fx : 1.f - fx) * (c1 ? fy : 1.f - fy);
      f0 += w * v.x;
      f1 += w * v.y;
    }
    int cb = enc * 8 + lev * 2;                      // emb column (concat: enc-major, level, feat)
    half2 hp = {(_Float16)(f0 * ALPHA), (_Float16)(f1 * ALPHA)};
    *(half2*)&hs[sw_idx(r, cb)] = hp;
  }
  // zero K-pad columns 16..31 for the first (K=32) MFMA
  for (int i = tid; i < MBLK * 16; i += 256) {
    int r = i >> 4, k = 16 + (i & 15);
    hs[sw_idx(r, k)] = (_Float16)0.f;
  }
  __syncthreads();

  floatx4 acc[4][4];

  // R12 A-address strength reduction. For A-reads, row = mt*16+col so row&7 =
  // col&7 and sw_idx's s is mt-independent:
  //   byte(mt,kc) = (mt*16+col)*512 + qa*16 + ((kc^s2)<<6)
  //   s_a=(col^(col>>1))&7, s2=s_a>>2, qa=quad^(s_a&3).
  // Exactly 2*sw_idx(mt*16+col, kc*32+quad*8) — verified algebraically (R3).
  // mt term (mt*8192) folds into the ds_read immediate offset.
  const int s_a = (col ^ (col >> 1)) & 7;
  const int s2  = (s_a >> 2) & 1;
  const int abase = col * 512 + (quad ^ (s_a & 3)) * 16;
  const char* const hsb = (const char*)hs;

  // One dense layer: D(64x256) = A(64xK) * B(Kx256); A = alpha*h (fp16, LDS),
  // B = fp16 weights (pre-permuted fragments, L2-resident).
  auto run_layer = [&](auto kc_const, const _Float16* __restrict__ wbase,
                       const float* __restrict__ bias_ptr) {
    constexpr int KCOUNT = decltype(kc_const)::value;
    const floatx4 zv = {0.f, 0.f, 0.f, 0.f};
    #pragma unroll
    for (int mt = 0; mt < 4; ++mt)
      #pragma unroll
      for (int nl = 0; nl < 4; ++nl)
        acc[mt][nl] = zv;

    const _Float16* wlane = wbase + wave * 4 * WNC_ELEMS + lane * 8;

    #pragma clang loop unroll(disable)               // keep VGPR pressure flat (<=128)
    for (int kc = 0; kc < KCOUNT; ++kc) {
      half8 b[4];
      const _Float16* wk = wlane + kc * WKC_ELEMS;
      #pragma unroll
      for (int nl = 0; nl < 4; ++nl)
        b[nl] = *(const half8*)(wk + nl * WNC_ELEMS);
      half8 a[4];
      const char* ap = hsb + abase + ((kc ^ s2) << 6);
      #pragma unroll
      for (int mt = 0; mt < 4; ++mt)
        a[mt] = *(const half8*)(ap + mt * 8192);     // imm-offset ds_read_b128
      __builtin_amdgcn_s_setprio(1);
      #pragma unroll
      for (int nl = 0; nl < 4; ++nl)
        #pragma unroll
        for (int mt = 0; mt < 4; ++mt)
          acc[mt][nl] = __builtin_amdgcn_mfma_f32_16x16x32_f16(a[mt], b[nl], acc[mt][nl], 0, 0, 0);
      __builtin_amdgcn_s_setprio(0);
    }
    __syncthreads();   // all waves done reading hs before overwrite
    #pragma unroll
    for (int nl = 0; nl < 4; ++nl) {
      int n = wave * 64 + nl * 16 + col;
      float biasA = bias_ptr[n] * ALPHA;             // bias scaled by alpha
      #pragma unroll
      for (int mt = 0; mt < 4; ++mt) {
        #pragma unroll
        for (int r = 0; r < 4; ++r) {
          // D layout: col = lane&15, row = quad*4 + r
          int m = mt * 16 + quad * 4 + r;
          float hv = fmaxf(acc[mt][nl][r] + biasA, 0.f);   // ReLU pre-next-matmul
          hs[sw_idx(m, n)] = (_Float16)hv;
        }
      }
    }
    __syncthreads();
  };

  run_layer(std::integral_constant<int, 1>{}, wsh, b_in);
  #pragma clang loop unroll(disable)
  for (int L = 0; L < NMID; ++L)
    run_layer(std::integral_constant<int, 8>{}, wsh + WIN_ELEMS + L * WL_ELEMS, b_mid + L * DIM);

  // ---------------- output layer: out = (alpha*relu h).W_out / alpha + b_out ----
  // R9: vectorized epilogue. sw_idx keeps k's low 3 bits contiguous, so an
  // 8-aligned half8 LDS read is legal: 8x ds_read_b128 + 16x float4 W_out loads
  // replace 64 ds_read_u16 + 64 scalar global loads per thread.
  {
    int m = tid >> 2, seg = tid & 3;          // same-m threads adjacent -> shuffle reduce
    float sum = 0.f;
    #pragma unroll
    for (int i = 0; i < 8; ++i) {
      int k = (seg << 6) + (i << 3);          // 8-aligned group within this thread's 64-wide segment
      half8 hv = *(const half8*)&hs[sw_idx(m, k)];
      float4 w0 = *(const float4*)&W_out[k];
      float4 w1 = *(const float4*)&W_out[k + 4];
      sum += (float)hv[0] * w0.x + (float)hv[1] * w0.y
           + (float)hv[2] * w0.z + (float)hv[3] * w0.w
           + (float)hv[4] * w1.x + (float)hv[5] * w1.y
           + (float)hv[6] * w1.z + (float)hv[7] * w1.w;
    }
    sum += __shfl_xor(sum, 1);
    sum += __shfl_xor(sum, 2);
    if (seg == 0) out[rbase + m] = sum * INV_ALPHA + b_out[0];
  }
}

extern "C" void kernel_launch(void* const* d_in, const int* in_sizes, int n_in,
                              void* d_out, int out_size, void* d_ws, size_t ws_size,
                              hipStream_t stream)
{
  const float* x      = (const float*)d_in[0];
  const float* table1 = (const float*)d_in[1];
  const float* table2 = (const float*)d_in[2];
  const float* W_in   = (const float*)d_in[3];
  const float* b_in   = (const float*)d_in[4];
  const float* W_mid  = (const float*)d_in[5];
  const float* b_mid  = (const float*)d_in[6];
  const float* W_out  = (const float*)d_in[7];
  const float* b_out  = (const float*)d_in[8];
  float* out  = (float*)d_out;
  _Float16* wsh = (_Float16*)d_ws;

  // Resolutions: identical double-precision op sequence as the Python module (same libm).
  double b = exp((log(512.0) - log(16.0)) / 3.0);
  int res[4];
  for (int l = 0; l < 4; ++l) res[l] = (int)floor(16.0 * pow(b, (double)l));

  int prep_total = WIN_ELEMS + 6 * WL_ELEMS;   // 401408 = 1568 * 256
  prep_weights<<<prep_total / 256, 256, 0, stream>>>(W_in, W_mid, wsh);
  mlp_fused<<<NRAYS / MBLK, 256, 0, stream>>>(x, table1, table2, wsh, b_in, b_mid,
                                              W_out, b_out, out,
                                              res[0], res[1], res[2], res[3]);
}

// Round 5
// 288.566 us; speedup vs baseline: 1.5166x; 1.3892x over previous
//
#include <hip/hip_runtime.h>
#include <type_traits>
#include <cmath>
#include <cstdint>

#define NRAYS     262144
#define HASHMAP   524288
#define DIM       256
#define NMID      6
#define MBLK      64
#define ALPHA     512.0f          // power-of-2 activation scale: lifts h (~1e-4) out of
#define INV_ALPHA (1.0f / 512.0f) // fp16 subnormal range; exact, removed at output.

typedef _Float16 half8 __attribute__((ext_vector_type(8)));
typedef _Float16 half2 __attribute__((ext_vector_type(2)));
typedef float  floatx4 __attribute__((ext_vector_type(4)));

// ws layout (_Float16 elements) — fp16 weights, single product per MFMA:
//   [0, 8192):        W_in  fragments [nc:16][lane:64][j:8]  (K padded 16->32 with zeros)
//   [8192, 401408):   W_mid fragments [L:6][kc:8][nc:16][lane:64][j:8]
// fp16 numerics validated (R7 pass): absmax 1.19e-7, 3.3x under threshold.
//
// SESSION INVARIANT (R10/R11 post-mortems): the ~4-7e-6 few-elements-wrong
// miscompile class fires whenever arch-side register demand exceeds the 64-reg
// half of the (256,4) 128-cap split. R9/R12 pass at exactly arch=64 + acc=64.
// Rules:
//   (a) NEVER swap MFMA operand roles;
//   (b) NEVER add pre-MFMA register state beyond b[4]+a[4] (no prefetch
//       double-buffers, no extra pre-barrier state) — only REDUCE;
//   (c) floatx4 accumulators only; launch_bounds (256,4) stays.
//
// R12 (passed, 326 us steady): strength-reduced A addressing + s_setprio.
// R13: same trick for the layer-epilogue writes (the dominant VALU block:
// ~8 instr/element x 64 x 7 layers, serial between barriers). All new temps
// are epilogue-local (b/a dead there) — no pre-MFMA state added.
// Conflict counter note (R4 decoded): 1.37e7 = 784 ds_read_b128/block x ~4 cyc
// natural multi-bank pattern; epilogue b16 writes verified conflict-free. Dead end.
#define WIN_ELEMS   8192
#define WL_ELEMS    65536
#define WKC_ELEMS   8192
#define WNC_ELEMS   512

// Gray-coded XOR swizzle (R4, frozen — conflict counter insensitive to choice).
__device__ __forceinline__ int sw_idx(int r, int k) {
  int s = (r ^ (r >> 1)) & 7;
  return (r << 8) + ((((k >> 3) ^ s) << 3) | (k & 7));
}

__global__ __launch_bounds__(256) void prep_weights(
    const float* __restrict__ W_in, const float* __restrict__ W_mid,
    _Float16* __restrict__ wsh)
{
  int tid = blockIdx.x * 256 + threadIdx.x;
  int pos = tid & 511;             // lane*8 + j
  int lane = pos >> 3, j = pos & 7;
  int kk = ((lane >> 4) << 3) + j; // quad*8 + j, 0..31
  if (tid < WIN_ELEMS) {
    int nc = tid >> 9;
    int n = (nc << 4) + (lane & 15);
    float v = (kk < 16) ? W_in[kk * DIM + n] : 0.f;
    wsh[nc * WNC_ELEMS + pos] = (_Float16)v;
  } else if (tid < WIN_ELEMS + 6 * WL_ELEMS) {
    int u = tid - WIN_ELEMS;
    int fid = u >> 9;              // 0..767
    int L   = fid >> 7;
    int rem = fid & 127;
    int kc  = rem >> 4;
    int nc  = rem & 15;
    int k = (kc << 5) + kk;
    int n = (nc << 4) + (lane & 15);
    float v = W_mid[L * (DIM * DIM) + k * DIM + n];
    wsh[WIN_ELEMS + L * WL_ELEMS + kc * WKC_ELEMS + nc * WNC_ELEMS + pos] = (_Float16)v;
  }
}

// (256,4): VGPR cap 128 (the correctness invariant) AND 4 blocks/CU (32 KB LDS)
// for cross-block phase overlap. Latency hiding via TLP (16 waves/CU), not
// register prefetch: per kc, 4 waves x 16 MFMA (~300 cyc/SIMD) covers ~200-cyc
// L2 latency of the un-prefetched weight loads.
__global__ __launch_bounds__(256, 4) void mlp_fused(
    const float* __restrict__ x,
    const float* __restrict__ table1,
    const float* __restrict__ table2,
    const _Float16* __restrict__ wsh,
    const float* __restrict__ b_in,
    const float* __restrict__ b_mid,
    const float* __restrict__ W_out,
    const float* __restrict__ b_out,
    float* __restrict__ out,
    int res0, int res1, int res2, int res3)
{
  __shared__ __align__(16) _Float16 hs[MBLK * 256];  // alpha*relu(h) in fp16, swizzled [ray][k]

  const int tid  = threadIdx.x;
  const int lane = tid & 63;
  const int wave = tid >> 6;
  const int col  = lane & 15;
  const int quad = lane >> 4;
  const int rbase = blockIdx.x * MBLK;

  // ---------------- hash-grid encode: 512 (ray,enc,level) tasks, 2 per thread ----------------
  #pragma unroll
  for (int i = 0; i < 2; ++i) {
    int task = tid + (i << 8);
    int r   = task & 63;
    int el  = task >> 6;           // 0..7
    int enc = el >> 2, lev = el & 3;
    const float* xp = x + (size_t)(rbase + r) * 4 + enc * 2;
    float px = xp[0], py = xp[1];
    int res = (lev == 0) ? res0 : (lev == 1) ? res1 : (lev == 2) ? res2 : res3;
    float fres = (float)res;
    float xf = px * fres, yf = py * fres;
    float xi = floorf(xf), yi = floorf(yf);
    float fx = xf - xi,  fy = yf - yi;
    uint32_t ix = (uint32_t)xi, iy = (uint32_t)yi;
    const float2* tab = (const float2*)(enc ? table2 : table1) + (size_t)lev * HASHMAP;
    float f0 = 0.f, f1 = 0.f;
    #pragma unroll
    for (int c = 0; c < 4; ++c) {                    // corners (0,0),(0,1),(1,0),(1,1)
      uint32_t c0 = (uint32_t)(c >> 1), c1 = (uint32_t)(c & 1);
      uint32_t h = ((ix + c0) ^ ((iy + c1) * 2654435761u)) & (uint32_t)(HASHMAP - 1);
      float2 v = tab[h];
      float w = (c0 ? fx : 1.f - fx) * (c1 ? fy : 1.f - fy);
      f0 += w * v.x;
      f1 += w * v.y;
    }
    int cb = enc * 8 + lev * 2;                      // emb column (concat: enc-major, level, feat)
    half2 hp = {(_Float16)(f0 * ALPHA), (_Float16)(f1 * ALPHA)};
    *(half2*)&hs[sw_idx(r, cb)] = hp;
  }
  // zero K-pad columns 16..31 for the first (K=32) MFMA
  for (int i = tid; i < MBLK * 16; i += 256) {
    int r = i >> 4, k = 16 + (i & 15);
    hs[sw_idx(r, k)] = (_Float16)0.f;
  }
  __syncthreads();

  floatx4 acc[4][4];

  // R12 A-address strength reduction. For A-reads, row = mt*16+col so row&7 =
  // col&7 and sw_idx's s is mt-independent:
  //   byte(mt,kc) = (mt*16+col)*512 + qa*16 + ((kc^s2)<<6)
  //   s_a=(col^(col>>1))&7, s2=s_a>>2, qa=quad^(s_a&3).
  // Exactly 2*sw_idx(mt*16+col, kc*32+quad*8) — verified algebraically (R3).
  // mt term (mt*8192) folds into the ds_read immediate offset.
  const int s_a = (col ^ (col >> 1)) & 7;
  const int s2  = (s_a >> 2) & 1;
  const int abase = col * 512 + (quad ^ (s_a & 3)) * 16;
  const char* const hsb = (const char*)hs;

  // One dense layer: D(64x256) = A(64xK) * B(Kx256); A = alpha*h (fp16, LDS),
  // B = fp16 weights (pre-permuted fragments, L2-resident).
  auto run_layer = [&](auto kc_const, const _Float16* __restrict__ wbase,
                       const float* __restrict__ bias_ptr) {
    constexpr int KCOUNT = decltype(kc_const)::value;
    const floatx4 zv = {0.f, 0.f, 0.f, 0.f};
    #pragma unroll
    for (int mt = 0; mt < 4; ++mt)
      #pragma unroll
      for (int nl = 0; nl < 4; ++nl)
        acc[mt][nl] = zv;

    const _Float16* wlane = wbase + wave * 4 * WNC_ELEMS + lane * 8;

    #pragma clang loop unroll(disable)               // keep VGPR pressure flat (<=128)
    for (int kc = 0; kc < KCOUNT; ++kc) {
      half8 b[4];
      const _Float16* wk = wlane + kc * WKC_ELEMS;
      #pragma unroll
      for (int nl = 0; nl < 4; ++nl)
        b[nl] = *(const half8*)(wk + nl * WNC_ELEMS);
      half8 a[4];
      const char* ap = hsb + abase + ((kc ^ s2) << 6);
      #pragma unroll
      for (int mt = 0; mt < 4; ++mt)
        a[mt] = *(const half8*)(ap + mt * 8192);     // imm-offset ds_read_b128
      __builtin_amdgcn_s_setprio(1);
      #pragma unroll
      for (int nl = 0; nl < 4; ++nl)
        #pragma unroll
        for (int mt = 0; mt < 4; ++mt)
          acc[mt][nl] = __builtin_amdgcn_mfma_f32_16x16x32_f16(a[mt], b[nl], acc[mt][nl], 0, 0, 0);
      __builtin_amdgcn_s_setprio(0);
    }
    __syncthreads();   // all waves done reading hs before overwrite

    // R13 epilogue address strength reduction. Write target (m,n):
    //   m = mt*16 + quad*4 + r, n = wave*64 + nl*16 + col.
    //   byte = m*512 + (((n>>3)^s(m))<<4) + (n&7)*2, s(m)=(m^(m>>1))&7.
    // s(m) uses only m bits 0..3 -> mt-independent: s_r = ((quad*4+r)^((quad*4+r)>>1))&7.
    // n>>3 = wave*8 + (nl*2|c3) with c3 = col>>3; XOR touches only bits 0..2:
    //   ((wave*8+v)^s_r) = wave*8 + (v^s_r), v = nl*2|c3.
    //   byte = mt*8192 (ds imm) + (quad*4+r)*512 + wave*128
    //        + ((v^s_r)<<4) + (col&7)*2.
    // Values & their arithmetic identical to R12; only addressing simplified.
    // All temps epilogue-local (b/a dead) -> no pre-MFMA register state.
    {
      const int c3   = (col >> 3) & 1;
      const int ebase = wave * 128 + ((col & 7) << 1);
      #pragma unroll
      for (int nl = 0; nl < 4; ++nl) {
        int n = wave * 64 + nl * 16 + col;
        float biasA = bias_ptr[n] * ALPHA;           // bias scaled by alpha
        #pragma unroll
        for (int r = 0; r < 4; ++r) {
          int m0  = quad * 4 + r;
          int s_r = (m0 ^ (m0 >> 1)) & 7;
          int va  = m0 * 512 + ebase + (((((nl << 1) | c3)) ^ s_r) << 4);
          char* wp = (char*)hs + va;
          #pragma unroll
          for (int mt = 0; mt < 4; ++mt) {
            float hv = fmaxf(acc[mt][nl][r] + biasA, 0.f);   // ReLU pre-next-matmul
            *(_Float16*)(wp + mt * 8192) = (_Float16)hv;     // imm-offset ds_write_b16
          }
        }
      }
    }
    __syncthreads();
  };

  run_layer(std::integral_constant<int, 1>{}, wsh, b_in);
  #pragma clang loop unroll(disable)
  for (int L = 0; L < NMID; ++L)
    run_layer(std::integral_constant<int, 8>{}, wsh + WIN_ELEMS + L * WL_ELEMS, b_mid + L * DIM);

  // ---------------- output layer: out = (alpha*relu h).W_out / alpha + b_out ----
  // R9: vectorized epilogue. sw_idx keeps k's low 3 bits contiguous, so an
  // 8-aligned half8 LDS read is legal: 8x ds_read_b128 + 16x float4 W_out loads
  // replace 64 ds_read_u16 + 64 scalar global loads per thread.
  {
    int m = tid >> 2, seg = tid & 3;          // same-m threads adjacent -> shuffle reduce
    float sum = 0.f;
    #pragma unroll
    for (int i = 0; i < 8; ++i) {
      int k = (seg << 6) + (i << 3);          // 8-aligned group within this thread's 64-wide segment
      half8 hv = *(const half8*)&hs[sw_idx(m, k)];
      float4 w0 = *(const float4*)&W_out[k];
      float4 w1 = *(const float4*)&W_out[k + 4];
      sum += (float)hv[0] * w0.x + (float)hv[1] * w0.y
           + (float)hv[2] * w0.z + (float)hv[3] * w0.w
           + (float)hv[4] * w1.x + (float)hv[5] * w1.y
           + (float)hv[6] * w1.z + (float)hv[7] * w1.w;
    }
    sum += __shfl_xor(sum, 1);
    sum += __shfl_xor(sum, 2);
    if (seg == 0) out[rbase + m] = sum * INV_ALPHA + b_out[0];
  }
}

extern "C" void kernel_launch(void* const* d_in, const int* in_sizes, int n_in,
                              void* d_out, int out_size, void* d_ws, size_t ws_size,
                              hipStream_t stream)
{
  const float* x      = (const float*)d_in[0];
  const float* table1 = (const float*)d_in[1];
  const float* table2 = (const float*)d_in[2];
  const float* W_in   = (const float*)d_in[3];
  const float* b_in   = (const float*)d_in[4];
  const float* W_mid  = (const float*)d_in[5];
  const float* b_mid  = (const float*)d_in[6];
  const float* W_out  = (const float*)d_in[7];
  const float* b_out  = (const float*)d_in[8];
  float* out  = (float*)d_out;
  _Float16* wsh = (_Float16*)d_ws;

  // Resolutions: identical double-precision op sequence as the Python module (same libm).
  double b = exp((log(512.0) - log(16.0)) / 3.0);
  int res[4];
  for (int l = 0; l < 4; ++l) res[l] = (int)floor(16.0 * pow(b, (double)l));

  int prep_total = WIN_ELEMS + 6 * WL_ELEMS;   // 401408 = 1568 * 256
  prep_weights<<<prep_total / 256, 256, 0, stream>>>(W_in, W_mid, wsh);
  mlp_fused<<<NRAYS / MBLK, 256, 0, stream>>>(x, table1, table2, wsh, b_in, b_mid,
                                              W_out, b_out, out,
                                              res[0], res[1], res[2], res[3]);
}